// Round 14
// baseline (197.474 us; speedup 1.0000x reference)
//
#include <hip/hip_runtime.h>

// VanillaGNN: out = A @ relu(A @ (x@W1)) @ W2, A[dst,src]=vals, all inputs f32.
// N=100000, E=1600000, IN=128, HID=128, OUT=64.
// Round-12 architecture + (a) h2 stored as fp8 e4m3 (64B rows = 1 line/edge,
// halves spmm2's L2-miss bytes; spmm is empirically pinned at ~3.5 TB/s of
// L2-miss traffic), (b) non-temporal sval loads so the 12.8MB edge stream
// doesn't evict gathered h rows from L2.

#define IN_CH  128
#define HID_CH 128
#define OUT_CH 64

typedef __attribute__((ext_vector_type(8))) short  bfrag8;   // 8 bf16 (MFMA A/B)
typedef __attribute__((ext_vector_type(4))) float  f32x4;    // MFMA C/D
typedef __attribute__((ext_vector_type(4))) unsigned short us4;
typedef __attribute__((ext_vector_type(8))) unsigned short us8;
typedef unsigned long long ull;

__device__ __forceinline__ unsigned short f2bf(float f) {
    unsigned u = __float_as_uint(f);
    u += 0x7FFFu + ((u >> 16) & 1u);   // round-to-nearest-even
    return (unsigned short)(u >> 16);
}
__device__ __forceinline__ float bf2f(unsigned short u) {
    return __uint_as_float(((unsigned)u) << 16);
}
// f32 -> fp8 e4m3 (OCP), RNE. Valid for |f| <= 448 (h2 max ~15).
__device__ __forceinline__ unsigned char f2fp8(float f) {
    unsigned u = __float_as_uint(f * 0x1p-120f);
    u += 0x7FFFFu + ((u >> 20) & 1u);
    return (unsigned char)(((u >> 24) & 0x80u) | ((u >> 20) & 0x7Fu));
}
// 4 packed fp8 e4m3 -> 4 f32 (handles denormals via f32 denormal path).
__device__ __forceinline__ void fp8x4_to_f32(unsigned w, float* f) {
    #pragma unroll
    for (int k = 0; k < 4; ++k) {
        unsigned b = (w >> (8 * k)) & 0xFFu;
        unsigned u = ((b & 0x80u) << 24) | ((b & 0x7Fu) << 20);
        f[k] = __uint_as_float(u) * 0x1p120f;
    }
}

// ---------------- CSR build (no global atomics) ----------------

__global__ __launch_bounds__(256) void cnt1(const int* __restrict__ dst,
                                            int* __restrict__ bcnt,
                                            int E, int CH, int NBUCK, int G1) {
    __shared__ int hist[512];
    const int blk = blockIdx.x, t = threadIdx.x;
    for (int j = t; j < NBUCK; j += 256) hist[j] = 0;
    __syncthreads();
    const int lo = blk * CH;
    const int hi = (lo + CH < E) ? lo + CH : E;
    for (int i = lo + t; i < hi; i += 256)
        atomicAdd(&hist[dst[i] >> 8], 1);
    __syncthreads();
    for (int j = t; j < NBUCK; j += 256) bcnt[(size_t)j * G1 + blk] = hist[j];
}

__global__ __launch_bounds__(1024) void scanA(const int* __restrict__ counts,
                                              int* __restrict__ excl,
                                              int* __restrict__ btot, int n) {
    __shared__ int wex[16];
    int t = threadIdx.x, lane = t & 63, w = t >> 6;
    int i = blockIdx.x * 1024 + t;
    int v = (i < n) ? counts[i] : 0;
    int s = v;
    #pragma unroll
    for (int d = 1; d < 64; d <<= 1) {
        int u = __shfl_up(s, d, 64);
        if (lane >= d) s += u;
    }
    if (lane == 63) wex[w] = s;
    __syncthreads();
    if (t == 0) {
        int run = 0;
        #pragma unroll
        for (int j = 0; j < 16; ++j) { int x = wex[j]; wex[j] = run; run += x; }
        btot[blockIdx.x] = run;
    }
    __syncthreads();
    if (i < n) excl[i] = wex[w] + (s - v);
}

__global__ __launch_bounds__(512) void scanB(int* __restrict__ btot, int nblk) {
    __shared__ int wsum[8];
    int t = threadIdx.x, lane = t & 63, w = t >> 6;
    int v = (t < nblk) ? btot[t] : 0;
    int s = v;
    #pragma unroll
    for (int d = 1; d < 64; d <<= 1) {
        int u = __shfl_up(s, d, 64);
        if (lane >= d) s += u;
    }
    if (lane == 63) wsum[w] = s;
    __syncthreads();
    if (t == 0) {
        int run = 0;
        #pragma unroll
        for (int j = 0; j < 8; ++j) { int x = wsum[j]; wsum[j] = run; run += x; }
    }
    __syncthreads();
    int excl = wsum[w] + (s - v);
    if (t < nblk) btot[t] = excl;
}

__global__ __launch_bounds__(1024) void scanC2(int* __restrict__ off,
                                               const int* __restrict__ btot, int n) {
    int i = blockIdx.x * 1024 + threadIdx.x;
    if (i < n) off[i] += btot[blockIdx.x];
}

__global__ void bbk(const int* __restrict__ off, int* __restrict__ bb,
                    int NBUCK, int G1, int E) {
    int t = threadIdx.x;
    if (t < NBUCK) bb[t] = off[(size_t)t * G1];
    if (t == NBUCK) bb[t] = E;
}

__global__ __launch_bounds__(256) void scat1(const int* __restrict__ src,
                                             const int* __restrict__ dst,
                                             const float* __restrict__ ev,
                                             const int* __restrict__ off,
                                             int2* __restrict__ ebuf,
                                             int E, int CH, int NBUCK, int G1) {
    __shared__ int cur[512];
    const int blk = blockIdx.x, t = threadIdx.x;
    for (int j = t; j < NBUCK; j += 256) cur[j] = off[(size_t)j * G1 + blk];
    __syncthreads();
    const int lo = blk * CH;
    const int hi = (lo + CH < E) ? lo + CH : E;
    for (int i = lo + t; i < hi; i += 256) {
        int d = dst[i];
        int pos = atomicAdd(&cur[d >> 8], 1);
        ebuf[pos] = make_int2(((d & 255) << 24) | src[i], __float_as_int(ev[i]));
    }
}

__global__ __launch_bounds__(256) void sort2(const int2* __restrict__ ebuf,
                                             const int* __restrict__ bb,
                                             int2* __restrict__ sval,
                                             int* __restrict__ row_ptr,
                                             int N, int NBUCK, int E) {
    __shared__ int hist[256];
    __shared__ int cur[256];
    __shared__ int wsum[4];
    const int b = blockIdx.x, t = threadIdx.x;
    const int base = bb[b];
    const int cnt = bb[b + 1] - base;
    hist[t] = 0;
    __syncthreads();
    for (int i = base + t; i < base + cnt; i += 256)
        atomicAdd(&hist[(unsigned)ebuf[i].x >> 24], 1);
    __syncthreads();
    int lane = t & 63, w = t >> 6;
    int v = hist[t], s = v;
    #pragma unroll
    for (int d = 1; d < 64; d <<= 1) {
        int u = __shfl_up(s, d, 64);
        if (lane >= d) s += u;
    }
    if (lane == 63) wsum[w] = s;
    __syncthreads();
    if (t == 0) {
        int run = 0;
        #pragma unroll
        for (int j = 0; j < 4; ++j) { int x = wsum[j]; wsum[j] = run; run += x; }
    }
    __syncthreads();
    int excl = wsum[w] + (s - v);
    int node = (b << 8) + t;
    if (node < N) row_ptr[node] = base + excl;
    if (b == NBUCK - 1 && t == 0) row_ptr[N] = E;
    cur[t] = excl;
    __syncthreads();
    for (int i = base + t; i < base + cnt; i += 256) {
        int2 e = ebuf[i];
        int bin = (unsigned)e.x >> 24;
        int pos = base + atomicAdd(&cur[bin], 1);
        sval[pos] = make_int2(e.x & 0xFFFFFF, e.y);
    }
}

// ---------------- weight cast+transpose (tiny) ----------------

__global__ void castT_w1(const float* __restrict__ W, unsigned short* __restrict__ WT) {
    int idx = blockIdx.x * 256 + threadIdx.x;
    int n = idx >> 7, k = idx & 127;
    WT[n * 128 + k] = f2bf(W[k * 128 + n]);
}
__global__ void castT_w2(const float* __restrict__ W, unsigned short* __restrict__ WT) {
    int idx = blockIdx.x * 256 + threadIdx.x;
    int n = idx >> 7, k = idx & 127;
    WT[n * 128 + k] = f2bf(W[(size_t)k * OUT_CH + n]);
}

// ---------------- GEMM1: h1 = bf16(x @ W1), MFMA 16x16x32 ----------------

__global__ __launch_bounds__(256) void gemm1_mfma(const float* __restrict__ X,
                                                  const unsigned short* __restrict__ W1T,
                                                  unsigned short* __restrict__ H1, int M) {
    __shared__ __align__(16) unsigned short As[128 * 136];
    __shared__ __align__(16) unsigned short Bs[128 * 136];
    const int tid = threadIdx.x;
    const int lane = tid & 63;
    const int w = tid >> 6;
    const int row0 = blockIdx.x * 128;

    #pragma unroll
    for (int l = 0; l < 16; ++l) {
        int f = tid + l * 256;
        int r = f >> 5, c4 = f & 31;
        int row = row0 + r;
        float4 v = make_float4(0.f, 0.f, 0.f, 0.f);
        if (row < M) v = *reinterpret_cast<const float4*>(&X[(size_t)row * IN_CH + c4 * 4]);
        us4 o; o[0] = f2bf(v.x); o[1] = f2bf(v.y); o[2] = f2bf(v.z); o[3] = f2bf(v.w);
        *reinterpret_cast<us4*>(&As[r * 136 + c4 * 4]) = o;
    }
    #pragma unroll
    for (int l = 0; l < 8; ++l) {
        int f = tid + l * 256;
        int n = f >> 4, k8 = f & 15;
        us8 v = *reinterpret_cast<const us8*>(&W1T[n * 128 + k8 * 8]);
        *reinterpret_cast<us8*>(&Bs[n * 136 + k8 * 8]) = v;
    }
    __syncthreads();

    f32x4 acc[2][8] = {};
    const int lr = lane & 15;
    const int kb = (lane >> 4) * 8;
    #pragma unroll
    for (int kk = 0; kk < 4; ++kk) {
        bfrag8 a0 = *reinterpret_cast<const bfrag8*>(&As[(w * 32 + lr) * 136 + kk * 32 + kb]);
        bfrag8 a1 = *reinterpret_cast<const bfrag8*>(&As[(w * 32 + 16 + lr) * 136 + kk * 32 + kb]);
        #pragma unroll
        for (int ni = 0; ni < 8; ++ni) {
            bfrag8 b = *reinterpret_cast<const bfrag8*>(&Bs[(ni * 16 + lr) * 136 + kk * 32 + kb]);
            acc[0][ni] = __builtin_amdgcn_mfma_f32_16x16x32_bf16(a0, b, acc[0][ni], 0, 0, 0);
            acc[1][ni] = __builtin_amdgcn_mfma_f32_16x16x32_bf16(a1, b, acc[1][ni], 0, 0, 0);
        }
    }
    const int rb = row0 + w * 32 + (lane >> 4) * 4;
    #pragma unroll
    for (int mi = 0; mi < 2; ++mi)
        #pragma unroll
        for (int j = 0; j < 4; ++j) {
            int row = rb + mi * 16 + j;
            if (row < M) {
                #pragma unroll
                for (int ni = 0; ni < 8; ++ni)
                    H1[(size_t)row * HID_CH + ni * 16 + lr] = f2bf(acc[mi][ni][j]);
            }
        }
}

// ---------------- GEMM2: h2 = fp8(g1r @ W2), A bf16 (relu pre-applied) ----------------
// Output is fp8 e4m3, row-major N x 64 bytes (one cache line per row).

__global__ __launch_bounds__(256) void gemm2_mfma(const unsigned short* __restrict__ G,
                                                  const unsigned short* __restrict__ W2T,
                                                  unsigned char* __restrict__ H2, int M) {
    __shared__ __align__(16) unsigned short As[128 * 136];
    __shared__ __align__(16) unsigned short Bs[64 * 136];
    const int tid = threadIdx.x;
    const int lane = tid & 63;
    const int w = tid >> 6;
    const int row0 = blockIdx.x * 128;

    #pragma unroll
    for (int l = 0; l < 8; ++l) {
        int f = tid + l * 256;
        int r = f >> 4, k8 = f & 15;
        int row = row0 + r;
        us8 v{};
        if (row < M) v = *reinterpret_cast<const us8*>(&G[(size_t)row * HID_CH + k8 * 8]);
        *reinterpret_cast<us8*>(&As[r * 136 + k8 * 8]) = v;
    }
    #pragma unroll
    for (int l = 0; l < 4; ++l) {
        int f = tid + l * 256;
        int n = f >> 4, k8 = f & 15;
        us8 v = *reinterpret_cast<const us8*>(&W2T[n * 128 + k8 * 8]);
        *reinterpret_cast<us8*>(&Bs[n * 136 + k8 * 8]) = v;
    }
    __syncthreads();

    f32x4 acc[2][4] = {};
    const int lr = lane & 15;
    const int kb = (lane >> 4) * 8;
    #pragma unroll
    for (int kk = 0; kk < 4; ++kk) {
        bfrag8 a0 = *reinterpret_cast<const bfrag8*>(&As[(w * 32 + lr) * 136 + kk * 32 + kb]);
        bfrag8 a1 = *reinterpret_cast<const bfrag8*>(&As[(w * 32 + 16 + lr) * 136 + kk * 32 + kb]);
        #pragma unroll
        for (int ni = 0; ni < 4; ++ni) {
            bfrag8 b = *reinterpret_cast<const bfrag8*>(&Bs[(ni * 16 + lr) * 136 + kk * 32 + kb]);
            acc[0][ni] = __builtin_amdgcn_mfma_f32_16x16x32_bf16(a0, b, acc[0][ni], 0, 0, 0);
            acc[1][ni] = __builtin_amdgcn_mfma_f32_16x16x32_bf16(a1, b, acc[1][ni], 0, 0, 0);
        }
    }
    const int rb = row0 + w * 32 + (lane >> 4) * 4;
    #pragma unroll
    for (int mi = 0; mi < 2; ++mi)
        #pragma unroll
        for (int j = 0; j < 4; ++j) {
            int row = rb + mi * 16 + j;
            if (row < M) {
                #pragma unroll
                for (int ni = 0; ni < 4; ++ni)
                    H2[(size_t)row * OUT_CH + ni * 16 + lr] = f2fp8(acc[mi][ni][j]);
            }
        }
}

// ---------------- SpMM layer 1: bf16 payload (D=128), nt sval loads ----------------

__global__ __launch_bounds__(256) void spmm1_bf16(const int* __restrict__ row_ptr,
                                                  const int2* __restrict__ sval,
                                                  const unsigned short* __restrict__ h,
                                                  unsigned short* __restrict__ outp, int n) {
    constexpr int TPN = 16;           // 16 lanes x 8 bf16
    constexpr int NPB = 256 / TPN;
    int node = blockIdx.x * NPB + threadIdx.x / TPN;
    if (node >= n) return;
    int c8 = (threadIdx.x % TPN) * 8;
    int s = row_ptr[node], e = row_ptr[node + 1];
    float acc[8] = {};
    int i = s;
    for (; i + 4 <= e; i += 4) {
        ull p0 = __builtin_nontemporal_load((const ull*)&sval[i + 0]);
        ull p1 = __builtin_nontemporal_load((const ull*)&sval[i + 1]);
        ull p2 = __builtin_nontemporal_load((const ull*)&sval[i + 2]);
        ull p3 = __builtin_nontemporal_load((const ull*)&sval[i + 3]);
        int sr0 = (int)(unsigned)p0, sr1 = (int)(unsigned)p1;
        int sr2 = (int)(unsigned)p2, sr3 = (int)(unsigned)p3;
        float v0 = __uint_as_float((unsigned)(p0 >> 32));
        float v1 = __uint_as_float((unsigned)(p1 >> 32));
        float v2 = __uint_as_float((unsigned)(p2 >> 32));
        float v3 = __uint_as_float((unsigned)(p3 >> 32));
        us8 m0 = *reinterpret_cast<const us8*>(&h[(size_t)sr0 * HID_CH + c8]);
        us8 m1 = *reinterpret_cast<const us8*>(&h[(size_t)sr1 * HID_CH + c8]);
        us8 m2 = *reinterpret_cast<const us8*>(&h[(size_t)sr2 * HID_CH + c8]);
        us8 m3 = *reinterpret_cast<const us8*>(&h[(size_t)sr3 * HID_CH + c8]);
        #pragma unroll
        for (int j = 0; j < 8; ++j) {
            acc[j] += v0 * bf2f(m0[j]);
            acc[j] += v1 * bf2f(m1[j]);
            acc[j] += v2 * bf2f(m2[j]);
            acc[j] += v3 * bf2f(m3[j]);
        }
    }
    for (; i < e; ++i) {
        ull p0 = __builtin_nontemporal_load((const ull*)&sval[i]);
        int sr = (int)(unsigned)p0;
        float v = __uint_as_float((unsigned)(p0 >> 32));
        us8 m = *reinterpret_cast<const us8*>(&h[(size_t)sr * HID_CH + c8]);
        #pragma unroll
        for (int j = 0; j < 8; ++j) acc[j] += v * bf2f(m[j]);
    }
    us8 o;
    #pragma unroll
    for (int j = 0; j < 8; ++j) o[j] = f2bf(fmaxf(acc[j], 0.f));
    *reinterpret_cast<us8*>(&outp[(size_t)node * HID_CH + c8]) = o;
}

// ---------------- SpMM layer 2: fp8 payload (D=64 = one line/row), f32 out ----------------

__global__ __launch_bounds__(256) void spmm2_fp8(const int* __restrict__ row_ptr,
                                                 const int2* __restrict__ sval,
                                                 const unsigned char* __restrict__ h,
                                                 float* __restrict__ out, int n) {
    constexpr int TPN = 8;            // 8 lanes x 8 fp8 bytes
    constexpr int NPB = 256 / TPN;    // 32 nodes/block
    int node = blockIdx.x * NPB + threadIdx.x / TPN;
    if (node >= n) return;
    int c8 = (threadIdx.x % TPN) * 8;
    int s = row_ptr[node], e = row_ptr[node + 1];
    float acc[8] = {};
    float f[8];
    int i = s;
    for (; i + 4 <= e; i += 4) {
        ull p0 = __builtin_nontemporal_load((const ull*)&sval[i + 0]);
        ull p1 = __builtin_nontemporal_load((const ull*)&sval[i + 1]);
        ull p2 = __builtin_nontemporal_load((const ull*)&sval[i + 2]);
        ull p3 = __builtin_nontemporal_load((const ull*)&sval[i + 3]);
        int sr0 = (int)(unsigned)p0, sr1 = (int)(unsigned)p1;
        int sr2 = (int)(unsigned)p2, sr3 = (int)(unsigned)p3;
        float v0 = __uint_as_float((unsigned)(p0 >> 32));
        float v1 = __uint_as_float((unsigned)(p1 >> 32));
        float v2 = __uint_as_float((unsigned)(p2 >> 32));
        float v3 = __uint_as_float((unsigned)(p3 >> 32));
        uint2 m0 = *reinterpret_cast<const uint2*>(&h[(size_t)sr0 * OUT_CH + c8]);
        uint2 m1 = *reinterpret_cast<const uint2*>(&h[(size_t)sr1 * OUT_CH + c8]);
        uint2 m2 = *reinterpret_cast<const uint2*>(&h[(size_t)sr2 * OUT_CH + c8]);
        uint2 m3 = *reinterpret_cast<const uint2*>(&h[(size_t)sr3 * OUT_CH + c8]);
        fp8x4_to_f32(m0.x, f); fp8x4_to_f32(m0.y, f + 4);
        #pragma unroll
        for (int j = 0; j < 8; ++j) acc[j] += v0 * f[j];
        fp8x4_to_f32(m1.x, f); fp8x4_to_f32(m1.y, f + 4);
        #pragma unroll
        for (int j = 0; j < 8; ++j) acc[j] += v1 * f[j];
        fp8x4_to_f32(m2.x, f); fp8x4_to_f32(m2.y, f + 4);
        #pragma unroll
        for (int j = 0; j < 8; ++j) acc[j] += v2 * f[j];
        fp8x4_to_f32(m3.x, f); fp8x4_to_f32(m3.y, f + 4);
        #pragma unroll
        for (int j = 0; j < 8; ++j) acc[j] += v3 * f[j];
    }
    for (; i < e; ++i) {
        ull p0 = __builtin_nontemporal_load((const ull*)&sval[i]);
        int sr = (int)(unsigned)p0;
        float v = __uint_as_float((unsigned)(p0 >> 32));
        uint2 m = *reinterpret_cast<const uint2*>(&h[(size_t)sr * OUT_CH + c8]);
        fp8x4_to_f32(m.x, f); fp8x4_to_f32(m.y, f + 4);
        #pragma unroll
        for (int j = 0; j < 8; ++j) acc[j] += v * f[j];
    }
    float* op = out + (size_t)node * OUT_CH + c8;
    *reinterpret_cast<float4*>(op)     = make_float4(acc[0], acc[1], acc[2], acc[3]);
    *reinterpret_cast<float4*>(op + 4) = make_float4(acc[4], acc[5], acc[6], acc[7]);
}

// ---------------- launch ----------------

extern "C" void kernel_launch(void* const* d_in, const int* in_sizes, int n_in,
                              void* d_out, int out_size, void* d_ws, size_t ws_size,
                              hipStream_t stream) {
    const float* x  = (const float*)d_in[0];
    const float* W1 = (const float*)d_in[1];
    const float* W2 = (const float*)d_in[2];
    const float* ev = (const float*)d_in[3];
    const int*   ei = (const int*)d_in[4];

    const int N = in_sizes[0] / IN_CH;   // 100000
    const int E = in_sizes[3];           // 1600000
    const int* src = ei;
    const int* dst = ei + E;

    const int NBUCK = (N + 255) >> 8;                    // 391
    const int G1 = 1024;                                 // level-1 blocks
    const int CH = (E + G1 - 1) / G1;                    // 1563 edges/block
    const int NB_TOT = NBUCK * G1;                       // 400384
    const int nchunk = (NB_TOT + 1023) / 1024;           // 392

    // persistent workspace (~64.5 MB)
    unsigned short* h1   = (unsigned short*)d_ws;        // N*128 bf16
    unsigned short* g1r  = h1 + (size_t)N * HID_CH;      // N*128 bf16 (relu applied)
    unsigned char*  h2   = (unsigned char*)h1;           // N*64 fp8 (alias, h1 dead after spmm1)
    unsigned short* w1t  = g1r + (size_t)N * HID_CH;     // 128*128 bf16 [n][k]
    unsigned short* w2t  = w1t + 128 * 128;              // 64*128 bf16 [n][k]
    int2*  sval    = (int2*)(w2t + 64 * 128);            // E packed (src, val)
    int*   row_ptr = (int*)(sval + E);                   // N+1

    // CSR-build temporaries aliased into h1/g1r (dead until gemm1/spmm1)
    int2*  ebuf = (int2*)h1;                             // E
    int*   bcnt = (int*)g1r;                             // NB_TOT
    int*   btot = bcnt + NB_TOT;                         // 512
    int*   bb   = btot + 512;                            // NBUCK+1

    // CSR build (LDS atomics only)
    cnt1<<<G1, 256, 0, stream>>>(dst, bcnt, E, CH, NBUCK, G1);
    scanA<<<nchunk, 1024, 0, stream>>>(bcnt, bcnt, btot, NB_TOT);
    scanB<<<1, 512, 0, stream>>>(btot, nchunk);
    scanC2<<<nchunk, 1024, 0, stream>>>(bcnt, btot, NB_TOT);
    bbk<<<1, 512, 0, stream>>>(bcnt, bb, NBUCK, G1, E);
    scat1<<<G1, 256, 0, stream>>>(src, dst, ev, bcnt, ebuf, E, CH, NBUCK, G1);
    sort2<<<NBUCK, 256, 0, stream>>>(ebuf, bb, sval, row_ptr, N, NBUCK, E);

    // weights: cast + transpose to [n][k] bf16
    castT_w1<<<64, 256, 0, stream>>>(W1, w1t);
    castT_w2<<<32, 256, 0, stream>>>(W2, w2t);

    // layer 1
    gemm1_mfma<<<(N + 127) / 128, 256, 0, stream>>>(x, w1t, h1, N);
    spmm1_bf16<<<(N + 15) / 16, 256, 0, stream>>>(row_ptr, sval, h1, g1r, N);

    // layer 2
    gemm2_mfma<<<(N + 127) / 128, 256, 0, stream>>>(g1r, w2t, h2, N);
    spmm2_fp8<<<(N + 31) / 32, 256, 0, stream>>>(row_ptr, sval, h2, (float*)d_out, N);
}

// Round 15
// 185.632 us; speedup vs baseline: 1.0638x; 1.0638x over previous
//
#include <hip/hip_runtime.h>

// VanillaGNN: out = A @ relu(A @ (x@W1)) @ W2, A[dst,src]=vals, all inputs f32.
// N=100000, E=1600000, IN=128, HID=128, OUT=64.
// FINAL (round-12 verified optimum, 189.6us): atomic-free two-level counting
// sort CSR build + bf16 MFMA GEMMs + bf16-payload gather SpMM (4x ILP).
// SpMM is pinned at the L2-miss transaction ceiling (~3.5 TB/s effective,
// invariant to payload width/layout per rounds 7-14); fp8 and nt-load
// variants measured and reverted (round 14: no gain, absmax margin too thin).

#define IN_CH  128
#define HID_CH 128
#define OUT_CH 64

typedef __attribute__((ext_vector_type(8))) short  bfrag8;   // 8 bf16 (MFMA A/B)
typedef __attribute__((ext_vector_type(4))) float  f32x4;    // MFMA C/D
typedef __attribute__((ext_vector_type(4))) unsigned short us4;
typedef __attribute__((ext_vector_type(8))) unsigned short us8;

__device__ __forceinline__ unsigned short f2bf(float f) {
    unsigned u = __float_as_uint(f);
    u += 0x7FFFu + ((u >> 16) & 1u);   // round-to-nearest-even
    return (unsigned short)(u >> 16);
}
__device__ __forceinline__ float bf2f(unsigned short u) {
    return __uint_as_float(((unsigned)u) << 16);
}

// ---------------- CSR build (no global atomics) ----------------

__global__ __launch_bounds__(256) void cnt1(const int* __restrict__ dst,
                                            int* __restrict__ bcnt,
                                            int E, int CH, int NBUCK, int G1) {
    __shared__ int hist[512];
    const int blk = blockIdx.x, t = threadIdx.x;
    for (int j = t; j < NBUCK; j += 256) hist[j] = 0;
    __syncthreads();
    const int lo = blk * CH;
    const int hi = (lo + CH < E) ? lo + CH : E;
    for (int i = lo + t; i < hi; i += 256)
        atomicAdd(&hist[dst[i] >> 8], 1);
    __syncthreads();
    for (int j = t; j < NBUCK; j += 256) bcnt[(size_t)j * G1 + blk] = hist[j];
}

__global__ __launch_bounds__(1024) void scanA(const int* __restrict__ counts,
                                              int* __restrict__ excl,
                                              int* __restrict__ btot, int n) {
    __shared__ int wex[16];
    int t = threadIdx.x, lane = t & 63, w = t >> 6;
    int i = blockIdx.x * 1024 + t;
    int v = (i < n) ? counts[i] : 0;
    int s = v;
    #pragma unroll
    for (int d = 1; d < 64; d <<= 1) {
        int u = __shfl_up(s, d, 64);
        if (lane >= d) s += u;
    }
    if (lane == 63) wex[w] = s;
    __syncthreads();
    if (t == 0) {
        int run = 0;
        #pragma unroll
        for (int j = 0; j < 16; ++j) { int x = wex[j]; wex[j] = run; run += x; }
        btot[blockIdx.x] = run;
    }
    __syncthreads();
    if (i < n) excl[i] = wex[w] + (s - v);
}

__global__ __launch_bounds__(512) void scanB(int* __restrict__ btot, int nblk) {
    __shared__ int wsum[8];
    int t = threadIdx.x, lane = t & 63, w = t >> 6;
    int v = (t < nblk) ? btot[t] : 0;
    int s = v;
    #pragma unroll
    for (int d = 1; d < 64; d <<= 1) {
        int u = __shfl_up(s, d, 64);
        if (lane >= d) s += u;
    }
    if (lane == 63) wsum[w] = s;
    __syncthreads();
    if (t == 0) {
        int run = 0;
        #pragma unroll
        for (int j = 0; j < 8; ++j) { int x = wsum[j]; wsum[j] = run; run += x; }
    }
    __syncthreads();
    int excl = wsum[w] + (s - v);
    if (t < nblk) btot[t] = excl;
}

__global__ __launch_bounds__(1024) void scanC2(int* __restrict__ off,
                                               const int* __restrict__ btot, int n) {
    int i = blockIdx.x * 1024 + threadIdx.x;
    if (i < n) off[i] += btot[blockIdx.x];
}

__global__ void bbk(const int* __restrict__ off, int* __restrict__ bb,
                    int NBUCK, int G1, int E) {
    int t = threadIdx.x;
    if (t < NBUCK) bb[t] = off[(size_t)t * G1];
    if (t == NBUCK) bb[t] = E;
}

__global__ __launch_bounds__(256) void scat1(const int* __restrict__ src,
                                             const int* __restrict__ dst,
                                             const float* __restrict__ ev,
                                             const int* __restrict__ off,
                                             int2* __restrict__ ebuf,
                                             int E, int CH, int NBUCK, int G1) {
    __shared__ int cur[512];
    const int blk = blockIdx.x, t = threadIdx.x;
    for (int j = t; j < NBUCK; j += 256) cur[j] = off[(size_t)j * G1 + blk];
    __syncthreads();
    const int lo = blk * CH;
    const int hi = (lo + CH < E) ? lo + CH : E;
    for (int i = lo + t; i < hi; i += 256) {
        int d = dst[i];
        int pos = atomicAdd(&cur[d >> 8], 1);
        ebuf[pos] = make_int2(((d & 255) << 24) | src[i], __float_as_int(ev[i]));
    }
}

__global__ __launch_bounds__(256) void sort2(const int2* __restrict__ ebuf,
                                             const int* __restrict__ bb,
                                             int2* __restrict__ sval,
                                             int* __restrict__ row_ptr,
                                             int N, int NBUCK, int E) {
    __shared__ int hist[256];
    __shared__ int cur[256];
    __shared__ int wsum[4];
    const int b = blockIdx.x, t = threadIdx.x;
    const int base = bb[b];
    const int cnt = bb[b + 1] - base;
    hist[t] = 0;
    __syncthreads();
    for (int i = base + t; i < base + cnt; i += 256)
        atomicAdd(&hist[(unsigned)ebuf[i].x >> 24], 1);
    __syncthreads();
    int lane = t & 63, w = t >> 6;
    int v = hist[t], s = v;
    #pragma unroll
    for (int d = 1; d < 64; d <<= 1) {
        int u = __shfl_up(s, d, 64);
        if (lane >= d) s += u;
    }
    if (lane == 63) wsum[w] = s;
    __syncthreads();
    if (t == 0) {
        int run = 0;
        #pragma unroll
        for (int j = 0; j < 4; ++j) { int x = wsum[j]; wsum[j] = run; run += x; }
    }
    __syncthreads();
    int excl = wsum[w] + (s - v);
    int node = (b << 8) + t;
    if (node < N) row_ptr[node] = base + excl;
    if (b == NBUCK - 1 && t == 0) row_ptr[N] = E;
    cur[t] = excl;
    __syncthreads();
    for (int i = base + t; i < base + cnt; i += 256) {
        int2 e = ebuf[i];
        int bin = (unsigned)e.x >> 24;
        int pos = base + atomicAdd(&cur[bin], 1);
        sval[pos] = make_int2(e.x & 0xFFFFFF, e.y);
    }
}

// ---------------- weight cast+transpose (tiny) ----------------

__global__ void castT_w1(const float* __restrict__ W, unsigned short* __restrict__ WT) {
    int idx = blockIdx.x * 256 + threadIdx.x;
    int n = idx >> 7, k = idx & 127;
    WT[n * 128 + k] = f2bf(W[k * 128 + n]);
}
__global__ void castT_w2(const float* __restrict__ W, unsigned short* __restrict__ WT) {
    int idx = blockIdx.x * 256 + threadIdx.x;
    int n = idx >> 7, k = idx & 127;
    WT[n * 128 + k] = f2bf(W[(size_t)k * OUT_CH + n]);
}

// ---------------- GEMM1: h1 = bf16(x @ W1), MFMA 16x16x32 ----------------

__global__ __launch_bounds__(256) void gemm1_mfma(const float* __restrict__ X,
                                                  const unsigned short* __restrict__ W1T,
                                                  unsigned short* __restrict__ H1, int M) {
    __shared__ __align__(16) unsigned short As[128 * 136];
    __shared__ __align__(16) unsigned short Bs[128 * 136];
    const int tid = threadIdx.x;
    const int lane = tid & 63;
    const int w = tid >> 6;
    const int row0 = blockIdx.x * 128;

    #pragma unroll
    for (int l = 0; l < 16; ++l) {
        int f = tid + l * 256;
        int r = f >> 5, c4 = f & 31;
        int row = row0 + r;
        float4 v = make_float4(0.f, 0.f, 0.f, 0.f);
        if (row < M) v = *reinterpret_cast<const float4*>(&X[(size_t)row * IN_CH + c4 * 4]);
        us4 o; o[0] = f2bf(v.x); o[1] = f2bf(v.y); o[2] = f2bf(v.z); o[3] = f2bf(v.w);
        *reinterpret_cast<us4*>(&As[r * 136 + c4 * 4]) = o;
    }
    #pragma unroll
    for (int l = 0; l < 8; ++l) {
        int f = tid + l * 256;
        int n = f >> 4, k8 = f & 15;
        us8 v = *reinterpret_cast<const us8*>(&W1T[n * 128 + k8 * 8]);
        *reinterpret_cast<us8*>(&Bs[n * 136 + k8 * 8]) = v;
    }
    __syncthreads();

    f32x4 acc[2][8] = {};
    const int lr = lane & 15;
    const int kb = (lane >> 4) * 8;
    #pragma unroll
    for (int kk = 0; kk < 4; ++kk) {
        bfrag8 a0 = *reinterpret_cast<const bfrag8*>(&As[(w * 32 + lr) * 136 + kk * 32 + kb]);
        bfrag8 a1 = *reinterpret_cast<const bfrag8*>(&As[(w * 32 + 16 + lr) * 136 + kk * 32 + kb]);
        #pragma unroll
        for (int ni = 0; ni < 8; ++ni) {
            bfrag8 b = *reinterpret_cast<const bfrag8*>(&Bs[(ni * 16 + lr) * 136 + kk * 32 + kb]);
            acc[0][ni] = __builtin_amdgcn_mfma_f32_16x16x32_bf16(a0, b, acc[0][ni], 0, 0, 0);
            acc[1][ni] = __builtin_amdgcn_mfma_f32_16x16x32_bf16(a1, b, acc[1][ni], 0, 0, 0);
        }
    }
    const int rb = row0 + w * 32 + (lane >> 4) * 4;
    #pragma unroll
    for (int mi = 0; mi < 2; ++mi)
        #pragma unroll
        for (int j = 0; j < 4; ++j) {
            int row = rb + mi * 16 + j;
            if (row < M) {
                #pragma unroll
                for (int ni = 0; ni < 8; ++ni)
                    H1[(size_t)row * HID_CH + ni * 16 + lr] = f2bf(acc[mi][ni][j]);
            }
        }
}

// ---------------- GEMM2: h2 = bf16(g1r @ W2), A already bf16 (relu pre-applied) ----------------

__global__ __launch_bounds__(256) void gemm2_mfma(const unsigned short* __restrict__ G,
                                                  const unsigned short* __restrict__ W2T,
                                                  unsigned short* __restrict__ H2, int M) {
    __shared__ __align__(16) unsigned short As[128 * 136];
    __shared__ __align__(16) unsigned short Bs[64 * 136];
    const int tid = threadIdx.x;
    const int lane = tid & 63;
    const int w = tid >> 6;
    const int row0 = blockIdx.x * 128;

    #pragma unroll
    for (int l = 0; l < 8; ++l) {
        int f = tid + l * 256;
        int r = f >> 4, k8 = f & 15;
        int row = row0 + r;
        us8 v{};
        if (row < M) v = *reinterpret_cast<const us8*>(&G[(size_t)row * HID_CH + k8 * 8]);
        *reinterpret_cast<us8*>(&As[r * 136 + k8 * 8]) = v;
    }
    #pragma unroll
    for (int l = 0; l < 4; ++l) {
        int f = tid + l * 256;
        int n = f >> 4, k8 = f & 15;
        us8 v = *reinterpret_cast<const us8*>(&W2T[n * 128 + k8 * 8]);
        *reinterpret_cast<us8*>(&Bs[n * 136 + k8 * 8]) = v;
    }
    __syncthreads();

    f32x4 acc[2][4] = {};
    const int lr = lane & 15;
    const int kb = (lane >> 4) * 8;
    #pragma unroll
    for (int kk = 0; kk < 4; ++kk) {
        bfrag8 a0 = *reinterpret_cast<const bfrag8*>(&As[(w * 32 + lr) * 136 + kk * 32 + kb]);
        bfrag8 a1 = *reinterpret_cast<const bfrag8*>(&As[(w * 32 + 16 + lr) * 136 + kk * 32 + kb]);
        #pragma unroll
        for (int ni = 0; ni < 4; ++ni) {
            bfrag8 b = *reinterpret_cast<const bfrag8*>(&Bs[(ni * 16 + lr) * 136 + kk * 32 + kb]);
            acc[0][ni] = __builtin_amdgcn_mfma_f32_16x16x32_bf16(a0, b, acc[0][ni], 0, 0, 0);
            acc[1][ni] = __builtin_amdgcn_mfma_f32_16x16x32_bf16(a1, b, acc[1][ni], 0, 0, 0);
        }
    }
    const int rb = row0 + w * 32 + (lane >> 4) * 4;
    #pragma unroll
    for (int mi = 0; mi < 2; ++mi)
        #pragma unroll
        for (int j = 0; j < 4; ++j) {
            int row = rb + mi * 16 + j;
            if (row < M) {
                #pragma unroll
                for (int ni = 0; ni < 4; ++ni)
                    H2[(size_t)row * OUT_CH + ni * 16 + lr] = f2bf(acc[mi][ni][j]);
            }
        }
}

// ---------------- SpMM: out[i] = sum_e val[e] * h[src[e]], bf16 payload ----------------
// D/8 lanes per node, us8 (16B) gathers, 4x unrolled for gather ILP.
// MODE 0: out = f32. MODE 1: out = bf16(relu(acc)).

template <int D, int MODE>
__global__ __launch_bounds__(256) void spmm_bf16(const int* __restrict__ row_ptr,
                                                 const int2* __restrict__ sval,
                                                 const unsigned short* __restrict__ h,
                                                 void* __restrict__ outp, int n) {
    constexpr int TPN = D / 8;
    constexpr int NPB = 256 / TPN;
    int node = blockIdx.x * NPB + threadIdx.x / TPN;
    if (node >= n) return;
    int c8 = (threadIdx.x % TPN) * 8;
    int s = row_ptr[node], e = row_ptr[node + 1];
    float acc[8] = {};
    int i = s;
    for (; i + 4 <= e; i += 4) {
        int2 e0 = sval[i + 0], e1 = sval[i + 1], e2 = sval[i + 2], e3 = sval[i + 3];
        float v0 = __int_as_float(e0.y), v1 = __int_as_float(e1.y);
        float v2 = __int_as_float(e2.y), v3 = __int_as_float(e3.y);
        us8 m0 = *reinterpret_cast<const us8*>(&h[(size_t)e0.x * D + c8]);
        us8 m1 = *reinterpret_cast<const us8*>(&h[(size_t)e1.x * D + c8]);
        us8 m2 = *reinterpret_cast<const us8*>(&h[(size_t)e2.x * D + c8]);
        us8 m3 = *reinterpret_cast<const us8*>(&h[(size_t)e3.x * D + c8]);
        #pragma unroll
        for (int j = 0; j < 8; ++j) {
            acc[j] += v0 * bf2f(m0[j]);
            acc[j] += v1 * bf2f(m1[j]);
            acc[j] += v2 * bf2f(m2[j]);
            acc[j] += v3 * bf2f(m3[j]);
        }
    }
    for (; i < e; ++i) {
        int2 e0 = sval[i];
        float v = __int_as_float(e0.y);
        us8 m = *reinterpret_cast<const us8*>(&h[(size_t)e0.x * D + c8]);
        #pragma unroll
        for (int j = 0; j < 8; ++j) acc[j] += v * bf2f(m[j]);
    }
    if (MODE == 1) {
        us8 o;
        #pragma unroll
        for (int j = 0; j < 8; ++j) o[j] = f2bf(fmaxf(acc[j], 0.f));
        *reinterpret_cast<us8*>(&((unsigned short*)outp)[(size_t)node * D + c8]) = o;
    } else {
        float* op = (float*)outp;
        float4 w0 = make_float4(acc[0], acc[1], acc[2], acc[3]);
        float4 w1 = make_float4(acc[4], acc[5], acc[6], acc[7]);
        *reinterpret_cast<float4*>(&op[(size_t)node * D + c8]) = w0;
        *reinterpret_cast<float4*>(&op[(size_t)node * D + c8 + 4]) = w1;
    }
}

// ---------------- launch ----------------

extern "C" void kernel_launch(void* const* d_in, const int* in_sizes, int n_in,
                              void* d_out, int out_size, void* d_ws, size_t ws_size,
                              hipStream_t stream) {
    const float* x  = (const float*)d_in[0];
    const float* W1 = (const float*)d_in[1];
    const float* W2 = (const float*)d_in[2];
    const float* ev = (const float*)d_in[3];
    const int*   ei = (const int*)d_in[4];

    const int N = in_sizes[0] / IN_CH;   // 100000
    const int E = in_sizes[3];           // 1600000
    const int* src = ei;
    const int* dst = ei + E;

    const int NBUCK = (N + 255) >> 8;                    // 391
    const int G1 = 1024;                                 // level-1 blocks
    const int CH = (E + G1 - 1) / G1;                    // 1563 edges/block
    const int NB_TOT = NBUCK * G1;                       // 400384
    const int nchunk = (NB_TOT + 1023) / 1024;           // 392

    // persistent workspace (~64.5 MB)
    unsigned short* h1   = (unsigned short*)d_ws;        // N*128 bf16
    unsigned short* g1r  = h1 + (size_t)N * HID_CH;      // N*128 bf16 (relu applied)
    unsigned short* h2   = h1;                           // N*64 bf16 (alias, h1 dead after spmm1)
    unsigned short* w1t  = g1r + (size_t)N * HID_CH;     // 128*128 bf16 [n][k]
    unsigned short* w2t  = w1t + 128 * 128;              // 64*128 bf16 [n][k]
    int2*  sval    = (int2*)(w2t + 64 * 128);            // E packed (src, val)
    int*   row_ptr = (int*)(sval + E);                   // N+1

    // CSR-build temporaries aliased into h1/g1r (dead until gemm1/spmm1)
    int2*  ebuf = (int2*)h1;                             // E
    int*   bcnt = (int*)g1r;                             // NB_TOT
    int*   btot = bcnt + NB_TOT;                         // 512
    int*   bb   = btot + 512;                            // NBUCK+1

    // CSR build (LDS atomics only)
    cnt1<<<G1, 256, 0, stream>>>(dst, bcnt, E, CH, NBUCK, G1);
    scanA<<<nchunk, 1024, 0, stream>>>(bcnt, bcnt, btot, NB_TOT);
    scanB<<<1, 512, 0, stream>>>(btot, nchunk);
    scanC2<<<nchunk, 1024, 0, stream>>>(bcnt, btot, NB_TOT);
    bbk<<<1, 512, 0, stream>>>(bcnt, bb, NBUCK, G1, E);
    scat1<<<G1, 256, 0, stream>>>(src, dst, ev, bcnt, ebuf, E, CH, NBUCK, G1);
    sort2<<<NBUCK, 256, 0, stream>>>(ebuf, bb, sval, row_ptr, N, NBUCK, E);

    // weights: cast + transpose to [n][k] bf16
    castT_w1<<<64, 256, 0, stream>>>(W1, w1t);
    castT_w2<<<32, 256, 0, stream>>>(W2, w2t);

    // layer 1
    gemm1_mfma<<<(N + 127) / 128, 256, 0, stream>>>(x, w1t, h1, N);
    spmm_bf16<HID_CH, 1><<<(N + 15) / 16, 256, 0, stream>>>(row_ptr, sval, h1, g1r, N);

    // layer 2
    gemm2_mfma<<<(N + 127) / 128, 256, 0, stream>>>(g1r, w2t, h2, N);
    spmm_bf16<OUT_CH, 0><<<(N + 31) / 32, 256, 0, stream>>>(row_ptr, sval, h2, (float*)d_out, N);
}